// Round 2
// 533.249 us; speedup vs baseline: 1.3223x; 1.3223x over previous
//
#include <hip/hip_runtime.h>

#define NRES 768
#define CPAIR 128
#define CMSA 256

typedef float vfloat4 __attribute__((ext_vector_type(4)));

// pair_kernel: one block (256 threads = 4 waves) handles 256 consecutive pairs
// within one row i. Grid = 768 rows x 3 segments.
//
// Hot loop: each wave processes 4 pairs/iteration, 16 lanes per pair, lane t
// holds channels [4t..4t+3] and [64+4t..64+4t+3] (2x float4 = 32B/lane,
// 512B/pair, 2KB/wave-iter, fully coalesced). Layernorm reduction is a 4-step
// shfl_xor butterfly within each 16-lane group (shared by 4 pairs at once).
//
// All per-pair index math (distogram bin, rel_pos, rel_chain) is done ONCE per
// pair in a setup phase (1 thread = 1 pair) and packed into a 14-bit word in
// LDS: [bin+1 : 4b][p : 7b][eidx : 3b].
//
// Weight streams folded into 3 lookups:
//   Dtab[16][128]: row 0 = zeros (bin = -1), rows 1..15 = w_dgram
//   Etab[6][128]:  k<5 -> w_rel[66] + w_rel[67+k] (entity_same branch folded),
//                  k=5 -> w_rel[72]
//   w_rel[p]:      from global (33KB, L1/L2-hot)
//   cv = bt_pair + b_dgram + b_rel, g_pair: hoisted to per-lane registers.
__global__ __launch_bounds__(256) void pair_kernel(
    const int* __restrict__ aatype,
    const int* __restrict__ residue_index,
    const int* __restrict__ asym_id,
    const int* __restrict__ entity_id,
    const int* __restrict__ sym_id,
    const float* __restrict__ prev_pos,
    const float* __restrict__ prev_pair,
    const float* __restrict__ w_dgram,
    const float* __restrict__ b_dgram,
    const float* __restrict__ g_pair,
    const float* __restrict__ bt_pair,
    const float* __restrict__ w_rel,
    const float* __restrict__ b_rel,
    float* __restrict__ out_pair)
{
    __shared__ float Dtab[16][128];
    __shared__ float Etab[6][128];
    __shared__ unsigned short packs[256];

    const int tid = threadIdx.x;
    const int bx  = blockIdx.x;
    const int i   = bx / 3;                 // magic-mul div
    const int seg = bx - i * 3;
    const int j0  = seg * 256;

    // ---- stage distogram table (row 0 = zeros for bin==-1) ----
    for (int idx = tid; idx < 16 * 128; idx += 256) {
        const int r = idx >> 7, c = idx & 127;
        Dtab[r][c] = (r == 0) ? 0.0f : w_dgram[(r - 1) * 128 + c];
    }
    // ---- stage entity/chain combined table ----
    for (int idx = tid; idx < 6 * 128; idx += 256) {
        const int r = idx >> 7, c = idx & 127;
        const float wc = w_rel[(67 + r) * 128 + c];
        Etab[r][c] = (r < 5) ? (w_rel[66 * 128 + c] + wc) : wc;
    }

    // ---- per-pair packed indices: thread tid -> pair (i, j0+tid) ----
    {
        const int j  = j0 + tid;
        const int ai = (aatype[i] == 7) ? 1 : 3;   // GLY -> CA else CB
        const int aj = (aatype[j] == 7) ? 1 : 3;
        const float* pi = prev_pos + ((long)i * 37 + ai) * 3;
        const float* pj = prev_pos + ((long)j * 37 + aj) * 3;
        const float dx = pi[0] - pj[0];
        const float dy = pi[1] - pj[1];
        const float dz = pi[2] - pj[2];
        const float d2 = dx * dx + dy * dy + dz * dz;

        int bin = -1;
        #pragma unroll
        for (int b = 0; b < 15; ++b) {
            const float lo = 3.25f + 1.25f * (float)b;
            const float l2 = lo * lo;
            const float hi = lo + 1.25f;
            const float u2 = (b == 14) ? 1e8f : hi * hi;
            if (d2 > l2 && d2 < u2) bin = b;       // strict, matches reference
        }

        const bool asame = asym_id[i] == asym_id[j];
        int off = residue_index[i] - residue_index[j] + 32;
        off = min(max(off, 0), 64);
        const int p = asame ? off : 65;

        const bool esame = entity_id[i] == entity_id[j];
        int ch = sym_id[i] - sym_id[j] + 2;
        ch = min(max(ch, 0), 4);
        const int eidx = esame ? ch : 5;

        packs[tid] = (unsigned short)((bin + 1) | (p << 4) | (eidx << 11));
    }

    // ---- persistent per-lane channel vectors ----
    const int lane = tid & 63;
    const int wid  = tid >> 6;
    const int g    = lane >> 4;
    const int t    = lane & 15;
    const int c0   = t * 4;
    const int c1   = c0 + 64;

    const float4 gp0 = *(const float4*)(g_pair + c0);
    const float4 gp1 = *(const float4*)(g_pair + c1);
    float4 cv0, cv1;
    {
        const float4 a0 = *(const float4*)(bt_pair + c0);
        const float4 a1 = *(const float4*)(bt_pair + c1);
        const float4 b0 = *(const float4*)(b_dgram + c0);
        const float4 b1 = *(const float4*)(b_dgram + c1);
        const float4 r0 = *(const float4*)(b_rel + c0);
        const float4 r1 = *(const float4*)(b_rel + c1);
        cv0 = make_float4(a0.x + b0.x + r0.x, a0.y + b0.y + r0.y,
                          a0.z + b0.z + r0.z, a0.w + b0.w + r0.w);
        cv1 = make_float4(a1.x + b1.x + r1.x, a1.y + b1.y + r1.y,
                          a1.z + b1.z + r1.z, a1.w + b1.w + r1.w);
    }

    __syncthreads();

    const float* rowp = prev_pair + ((long)i * NRES + j0) * CPAIR;
    float*       outp = out_pair + ((long)i * NRES + j0) * CPAIR;

    #pragma unroll 2
    for (int k = 0; k < 16; ++k) {
        const int pl = (wid << 6) | (k << 2) | g;      // pair within block
        const unsigned int pk = packs[pl];             // LDS broadcast in group
        const int bidx = pk & 15;
        const int p    = (pk >> 4) & 127;
        const int eidx = (pk >> 11) & 7;

        const float* xp = rowp + (long)pl * CPAIR;
        const float4 x0 = *(const float4*)(xp + c0);
        const float4 x1 = *(const float4*)(xp + c1);

        const float* wr = w_rel + p * 128;
        const float4 w0 = *(const float4*)(wr + c0);
        const float4 w1 = *(const float4*)(wr + c1);
        const float4 d0 = *(const float4*)(&Dtab[bidx][c0]);
        const float4 d1 = *(const float4*)(&Dtab[bidx][c1]);
        const float4 e0 = *(const float4*)(&Etab[eidx][c0]);
        const float4 e1 = *(const float4*)(&Etab[eidx][c1]);

        // mean over 128 ch (16-lane butterfly; xor 1,2,4,8 stays in group)
        float s = ((x0.x + x0.y) + (x0.z + x0.w)) + ((x1.x + x1.y) + (x1.z + x1.w));
        #pragma unroll
        for (int m = 8; m >= 1; m >>= 1) s += __shfl_xor(s, m);
        const float mu = s * (1.0f / 128.0f);

        const float v0 = x0.x - mu, v1 = x0.y - mu, v2 = x0.z - mu, v3 = x0.w - mu;
        const float v4 = x1.x - mu, v5 = x1.y - mu, v6 = x1.z - mu, v7 = x1.w - mu;
        float vv = ((v0 * v0 + v1 * v1) + (v2 * v2 + v3 * v3)) +
                   ((v4 * v4 + v5 * v5) + (v6 * v6 + v7 * v7));
        #pragma unroll
        for (int m = 8; m >= 1; m >>= 1) vv += __shfl_xor(vv, m);
        const float rstd = rsqrtf(vv * (1.0f / 128.0f) + 1e-5f);

        vfloat4 o0, o1;
        o0.x = v0 * rstd * gp0.x + (cv0.x + d0.x + w0.x + e0.x);
        o0.y = v1 * rstd * gp0.y + (cv0.y + d0.y + w0.y + e0.y);
        o0.z = v2 * rstd * gp0.z + (cv0.z + d0.z + w0.z + e0.z);
        o0.w = v3 * rstd * gp0.w + (cv0.w + d0.w + w0.w + e0.w);
        o1.x = v4 * rstd * gp1.x + (cv1.x + d1.x + w1.x + e1.x);
        o1.y = v5 * rstd * gp1.y + (cv1.y + d1.y + w1.y + e1.y);
        o1.z = v6 * rstd * gp1.z + (cv1.z + d1.z + w1.z + e1.z);
        o1.w = v7 * rstd * gp1.w + (cv1.w + d1.w + w1.w + e1.w);

        // nt store: don't let the 295MB write stream evict prev_pair from L3
        float* op = outp + (long)pl * CPAIR;
        __builtin_nontemporal_store(o0, (vfloat4*)(op + c0));
        __builtin_nontemporal_store(o1, (vfloat4*)(op + c1));
    }
}

// One wave64 per residue row; lane l holds channels 4l..4l+3 (float4).
__global__ __launch_bounds__(256) void msa_kernel(
    const float* __restrict__ prev_msa,
    const float* __restrict__ g_msa,
    const float* __restrict__ bt_msa,
    float* __restrict__ out_msa)
{
    const int lane = threadIdx.x & 63;
    const int row = (int)((blockIdx.x * blockDim.x + threadIdx.x) >> 6);
    if (row >= NRES) return;

    const int c = lane * 4;
    const long base = (long)row * CMSA + c;
    const float4 x = *(const float4*)(prev_msa + base);

    float s = (x.x + x.y) + (x.z + x.w);
    #pragma unroll
    for (int m = 32; m >= 1; m >>= 1) s += __shfl_xor(s, m);
    const float mu = s * (1.0f / 256.0f);

    const float a0 = x.x - mu, a1 = x.y - mu, a2 = x.z - mu, a3 = x.w - mu;
    float v = (a0 * a0 + a1 * a1) + (a2 * a2 + a3 * a3);
    #pragma unroll
    for (int m = 32; m >= 1; m >>= 1) v += __shfl_xor(v, m);
    const float rstd = rsqrtf(v * (1.0f / 256.0f) + 1e-5f);

    const float4 g  = *(const float4*)(g_msa  + c);
    const float4 bt = *(const float4*)(bt_msa + c);
    float4 o;
    o.x = a0 * rstd * g.x + bt.x;
    o.y = a1 * rstd * g.y + bt.y;
    o.z = a2 * rstd * g.z + bt.z;
    o.w = a3 * rstd * g.w + bt.w;
    *(float4*)(out_msa + base) = o;
}

extern "C" void kernel_launch(void* const* d_in, const int* in_sizes, int n_in,
                              void* d_out, int out_size, void* d_ws, size_t ws_size,
                              hipStream_t stream) {
    const int*   aatype        = (const int*)d_in[0];
    const int*   residue_index = (const int*)d_in[1];
    const int*   asym_id       = (const int*)d_in[2];
    const int*   entity_id     = (const int*)d_in[3];
    const int*   sym_id        = (const int*)d_in[4];
    const float* prev_pos      = (const float*)d_in[5];
    const float* prev_pair     = (const float*)d_in[6];
    const float* prev_msa      = (const float*)d_in[7];
    const float* w_dgram       = (const float*)d_in[8];
    const float* b_dgram       = (const float*)d_in[9];
    const float* g_pair        = (const float*)d_in[10];
    const float* bt_pair       = (const float*)d_in[11];
    const float* g_msa         = (const float*)d_in[12];
    const float* bt_msa        = (const float*)d_in[13];
    const float* w_rel         = (const float*)d_in[14];
    const float* b_rel         = (const float*)d_in[15];

    float* out_msa  = (float*)d_out;                       // [768,256] first
    float* out_pair = out_msa + (long)NRES * CMSA;         // then [768,768,128]

    msa_kernel<<<(NRES * 64 + 255) / 256, 256, 0, stream>>>(
        prev_msa, g_msa, bt_msa, out_msa);

    pair_kernel<<<NRES * 3, 256, 0, stream>>>(
        aatype, residue_index, asym_id, entity_id, sym_id,
        prev_pos, prev_pair,
        w_dgram, b_dgram, g_pair, bt_pair, w_rel, b_rel,
        out_pair);
}

// Round 3
// 531.050 us; speedup vs baseline: 1.3278x; 1.0041x over previous
//
#include <hip/hip_runtime.h>

#define NRES 768
#define CPAIR 128
#define CMSA 256

typedef float vfloat4 __attribute__((ext_vector_type(4)));

// 16-lane rotate-reduce step via DPP (row_ror:N within each 16-lane row).
// Pure VALU: no DS traffic, no lgkmcnt wait. After ror 1,2,4,8 every lane in
// the 16-lane row holds the row sum.
template <int CTRL>
__device__ __forceinline__ float dpp_rot_add(float v) {
    const int r = __builtin_amdgcn_update_dpp(
        0, __float_as_int(v), CTRL, 0xF, 0xF, true);
    return v + __int_as_float(r);
}

// pair_kernel: one block (256 threads = 4 waves) handles 256 consecutive pairs
// within one row i. Grid = 768 rows x 3 segments.
//
// Hot loop: each wave processes 4 pairs/iteration, 16 lanes per pair, lane t
// holds channels [4t..4t+3] and [64+4t..64+4t+3] (2x float4 = 32B/lane,
// 512B/pair, 2KB/wave-iter, fully coalesced). Layernorm stats are one-pass
// (sum, sumsq) reduced by two independent 4-step DPP rotate chains.
//
// All per-pair index math (distogram bin, rel_pos, rel_chain) is done ONCE per
// pair in a setup phase (1 thread = 1 pair) and packed into a 14-bit word in
// LDS: [bin+1 : 4b][p : 7b][eidx : 3b].
//
// Weight streams folded into 3 lookups:
//   Dtab[16][128]: row 0 = zeros (bin = -1), rows 1..15 = w_dgram
//   Etab[6][128]:  cv + (k<5 ? w_rel[66]+w_rel[67+k] : w_rel[72]),
//                  where cv = bt_pair + b_dgram + b_rel (folded at staging)
//   w_rel[p]:      from global (33KB, L1/L2-hot)
__global__ __launch_bounds__(256) void pair_kernel(
    const int* __restrict__ aatype,
    const int* __restrict__ residue_index,
    const int* __restrict__ asym_id,
    const int* __restrict__ entity_id,
    const int* __restrict__ sym_id,
    const float* __restrict__ prev_pos,
    const float* __restrict__ prev_pair,
    const float* __restrict__ w_dgram,
    const float* __restrict__ b_dgram,
    const float* __restrict__ g_pair,
    const float* __restrict__ bt_pair,
    const float* __restrict__ w_rel,
    const float* __restrict__ b_rel,
    float* __restrict__ out_pair)
{
    __shared__ float Dtab[16][128];
    __shared__ float Etab[6][128];
    __shared__ unsigned short packs[256];

    const int tid = threadIdx.x;
    const int bx  = blockIdx.x;
    const int i   = bx / 3;                 // magic-mul div
    const int seg = bx - i * 3;
    const int j0  = seg * 256;

    // ---- stage distogram table (row 0 = zeros for bin==-1) ----
    for (int idx = tid; idx < 16 * 128; idx += 256) {
        const int r = idx >> 7, c = idx & 127;
        Dtab[r][c] = (r == 0) ? 0.0f : w_dgram[(r - 1) * 128 + c];
    }
    // ---- stage entity/chain table with constant bias vector folded in ----
    for (int idx = tid; idx < 6 * 128; idx += 256) {
        const int r = idx >> 7, c = idx & 127;
        const float cv = bt_pair[c] + b_dgram[c] + b_rel[c];
        const float wc = w_rel[(67 + r) * 128 + c];
        Etab[r][c] = cv + ((r < 5) ? (w_rel[66 * 128 + c] + wc) : wc);
    }

    // ---- per-pair packed indices: thread tid -> pair (i, j0+tid) ----
    {
        const int j  = j0 + tid;
        const int ai = (aatype[i] == 7) ? 1 : 3;   // GLY -> CA else CB
        const int aj = (aatype[j] == 7) ? 1 : 3;
        const float* pi = prev_pos + ((long)i * 37 + ai) * 3;
        const float* pj = prev_pos + ((long)j * 37 + aj) * 3;
        const float dx = pi[0] - pj[0];
        const float dy = pi[1] - pj[1];
        const float dz = pi[2] - pj[2];
        const float d2 = dx * dx + dy * dy + dz * dz;

        int bin = -1;
        #pragma unroll
        for (int b = 0; b < 15; ++b) {
            const float lo = 3.25f + 1.25f * (float)b;
            const float l2 = lo * lo;
            const float hi = lo + 1.25f;
            const float u2 = (b == 14) ? 1e8f : hi * hi;
            if (d2 > l2 && d2 < u2) bin = b;       // strict, matches reference
        }

        const bool asame = asym_id[i] == asym_id[j];
        int off = residue_index[i] - residue_index[j] + 32;
        off = min(max(off, 0), 64);
        const int p = asame ? off : 65;

        const bool esame = entity_id[i] == entity_id[j];
        int ch = sym_id[i] - sym_id[j] + 2;
        ch = min(max(ch, 0), 4);
        const int eidx = esame ? ch : 5;

        packs[tid] = (unsigned short)((bin + 1) | (p << 4) | (eidx << 11));
    }

    // ---- persistent per-lane channel vectors ----
    const int lane = tid & 63;
    const int wid  = tid >> 6;
    const int g    = lane >> 4;
    const int t    = lane & 15;
    const int c0   = t * 4;
    const int c1   = c0 + 64;

    const float4 gp0 = *(const float4*)(g_pair + c0);
    const float4 gp1 = *(const float4*)(g_pair + c1);

    __syncthreads();

    const float* rowp = prev_pair + ((long)i * NRES + j0) * CPAIR;
    float*       outp = out_pair + ((long)i * NRES + j0) * CPAIR;

    #pragma unroll 2
    for (int k = 0; k < 16; ++k) {
        const int pl = (wid << 6) | (k << 2) | g;      // pair within block
        const unsigned int pk = packs[pl];             // LDS broadcast in group
        const int bidx = pk & 15;
        const int p    = (pk >> 4) & 127;
        const int eidx = (pk >> 11) & 7;

        const float* xp = rowp + (long)pl * CPAIR;
        const float4 x0 = *(const float4*)(xp + c0);
        const float4 x1 = *(const float4*)(xp + c1);

        const float* wr = w_rel + p * 128;
        const float4 w0 = *(const float4*)(wr + c0);
        const float4 w1 = *(const float4*)(wr + c1);
        const float4 d0 = *(const float4*)(&Dtab[bidx][c0]);
        const float4 d1 = *(const float4*)(&Dtab[bidx][c1]);
        const float4 e0 = *(const float4*)(&Etab[eidx][c0]);
        const float4 e1 = *(const float4*)(&Etab[eidx][c1]);

        // one-pass stats: s = sum(x), q = sum(x^2); two independent DPP chains
        float s = ((x0.x + x0.y) + (x0.z + x0.w)) + ((x1.x + x1.y) + (x1.z + x1.w));
        float q = ((x0.x * x0.x + x0.y * x0.y) + (x0.z * x0.z + x0.w * x0.w)) +
                  ((x1.x * x1.x + x1.y * x1.y) + (x1.z * x1.z + x1.w * x1.w));
        s = dpp_rot_add<0x121>(s); q = dpp_rot_add<0x121>(q);  // ror 1
        s = dpp_rot_add<0x122>(s); q = dpp_rot_add<0x122>(q);  // ror 2
        s = dpp_rot_add<0x124>(s); q = dpp_rot_add<0x124>(q);  // ror 4
        s = dpp_rot_add<0x128>(s); q = dpp_rot_add<0x128>(q);  // ror 8

        const float mu = s * (1.0f / 128.0f);
        const float var = q * (1.0f / 128.0f) - mu * mu;
        const float rstd = rsqrtf(var + 1e-5f);

        const float v0 = x0.x - mu, v1 = x0.y - mu, v2 = x0.z - mu, v3 = x0.w - mu;
        const float v4 = x1.x - mu, v5 = x1.y - mu, v6 = x1.z - mu, v7 = x1.w - mu;

        vfloat4 o0, o1;
        o0.x = v0 * rstd * gp0.x + (d0.x + w0.x + e0.x);
        o0.y = v1 * rstd * gp0.y + (d0.y + w0.y + e0.y);
        o0.z = v2 * rstd * gp0.z + (d0.z + w0.z + e0.z);
        o0.w = v3 * rstd * gp0.w + (d0.w + w0.w + e0.w);
        o1.x = v4 * rstd * gp1.x + (d1.x + w1.x + e1.x);
        o1.y = v5 * rstd * gp1.y + (d1.y + w1.y + e1.y);
        o1.z = v6 * rstd * gp1.z + (d1.z + w1.z + e1.z);
        o1.w = v7 * rstd * gp1.w + (d1.w + w1.w + e1.w);

        // nt store: don't let the 295MB write stream evict prev_pair from L3
        float* op = outp + (long)pl * CPAIR;
        __builtin_nontemporal_store(o0, (vfloat4*)(op + c0));
        __builtin_nontemporal_store(o1, (vfloat4*)(op + c1));
    }
}

// One wave64 per residue row; lane l holds channels 4l..4l+3 (float4).
__global__ __launch_bounds__(256) void msa_kernel(
    const float* __restrict__ prev_msa,
    const float* __restrict__ g_msa,
    const float* __restrict__ bt_msa,
    float* __restrict__ out_msa)
{
    const int lane = threadIdx.x & 63;
    const int row = (int)((blockIdx.x * blockDim.x + threadIdx.x) >> 6);
    if (row >= NRES) return;

    const int c = lane * 4;
    const long base = (long)row * CMSA + c;
    const float4 x = *(const float4*)(prev_msa + base);

    float s = (x.x + x.y) + (x.z + x.w);
    #pragma unroll
    for (int m = 32; m >= 1; m >>= 1) s += __shfl_xor(s, m);
    const float mu = s * (1.0f / 256.0f);

    const float a0 = x.x - mu, a1 = x.y - mu, a2 = x.z - mu, a3 = x.w - mu;
    float v = (a0 * a0 + a1 * a1) + (a2 * a2 + a3 * a3);
    #pragma unroll
    for (int m = 32; m >= 1; m >>= 1) v += __shfl_xor(v, m);
    const float rstd = rsqrtf(v * (1.0f / 256.0f) + 1e-5f);

    const float4 g  = *(const float4*)(g_msa  + c);
    const float4 bt = *(const float4*)(bt_msa + c);
    float4 o;
    o.x = a0 * rstd * g.x + bt.x;
    o.y = a1 * rstd * g.y + bt.y;
    o.z = a2 * rstd * g.z + bt.z;
    o.w = a3 * rstd * g.w + bt.w;
    *(float4*)(out_msa + base) = o;
}

extern "C" void kernel_launch(void* const* d_in, const int* in_sizes, int n_in,
                              void* d_out, int out_size, void* d_ws, size_t ws_size,
                              hipStream_t stream) {
    const int*   aatype        = (const int*)d_in[0];
    const int*   residue_index = (const int*)d_in[1];
    const int*   asym_id       = (const int*)d_in[2];
    const int*   entity_id     = (const int*)d_in[3];
    const int*   sym_id        = (const int*)d_in[4];
    const float* prev_pos      = (const float*)d_in[5];
    const float* prev_pair     = (const float*)d_in[6];
    const float* prev_msa      = (const float*)d_in[7];
    const float* w_dgram       = (const float*)d_in[8];
    const float* b_dgram       = (const float*)d_in[9];
    const float* g_pair        = (const float*)d_in[10];
    const float* bt_pair       = (const float*)d_in[11];
    const float* g_msa         = (const float*)d_in[12];
    const float* bt_msa        = (const float*)d_in[13];
    const float* w_rel         = (const float*)d_in[14];
    const float* b_rel         = (const float*)d_in[15];

    float* out_msa  = (float*)d_out;                       // [768,256] first
    float* out_pair = out_msa + (long)NRES * CMSA;         // then [768,768,128]

    msa_kernel<<<(NRES * 64 + 255) / 256, 256, 0, stream>>>(
        prev_msa, g_msa, bt_msa, out_msa);

    pair_kernel<<<NRES * 3, 256, 0, stream>>>(
        aatype, residue_index, asym_id, entity_id, sym_id,
        prev_pos, prev_pair,
        w_dgram, b_dgram, g_pair, bt_pair, w_rel, b_rel,
        out_pair);
}

// Round 4
// 516.413 us; speedup vs baseline: 1.3654x; 1.0283x over previous
//
#include <hip/hip_runtime.h>

#define NRES 768
#define CPAIR 128
#define CMSA 256

// 16-lane rotate-reduce step via DPP (row_ror:N within each 16-lane row).
// Pure VALU: no DS traffic, no lgkmcnt wait. After ror 1,2,4,8 every lane in
// the 16-lane row holds the row sum.
template <int CTRL>
__device__ __forceinline__ float dpp_rot_add(float v) {
    const int r = __builtin_amdgcn_update_dpp(
        0, __float_as_int(v), CTRL, 0xF, 0xF, true);
    return v + __int_as_float(r);
}

// pair_kernel: one block (256 threads = 4 waves) handles 256 consecutive pairs
// within one row i. Grid = 768 rows x 3 segments.
//
// R4 A/B: identical to R3 except stores are plain float4 (NT removed).
// R0 evidence: without NT, L3 already absorbed ~half the prev_pair re-read
// (FETCH 148 MB vs 302 MB ideal); fill kernels prove regular stores hit
// 6.5 TB/s. Testing whether the nt store path is the 60 us over-floor cost.
__global__ __launch_bounds__(256) void pair_kernel(
    const int* __restrict__ aatype,
    const int* __restrict__ residue_index,
    const int* __restrict__ asym_id,
    const int* __restrict__ entity_id,
    const int* __restrict__ sym_id,
    const float* __restrict__ prev_pos,
    const float* __restrict__ prev_pair,
    const float* __restrict__ w_dgram,
    const float* __restrict__ b_dgram,
    const float* __restrict__ g_pair,
    const float* __restrict__ bt_pair,
    const float* __restrict__ w_rel,
    const float* __restrict__ b_rel,
    float* __restrict__ out_pair)
{
    __shared__ float Dtab[16][128];
    __shared__ float Etab[6][128];
    __shared__ unsigned short packs[256];

    const int tid = threadIdx.x;
    const int bx  = blockIdx.x;
    const int i   = bx / 3;                 // magic-mul div
    const int seg = bx - i * 3;
    const int j0  = seg * 256;

    // ---- stage distogram table (row 0 = zeros for bin==-1) ----
    for (int idx = tid; idx < 16 * 128; idx += 256) {
        const int r = idx >> 7, c = idx & 127;
        Dtab[r][c] = (r == 0) ? 0.0f : w_dgram[(r - 1) * 128 + c];
    }
    // ---- stage entity/chain table with constant bias vector folded in ----
    for (int idx = tid; idx < 6 * 128; idx += 256) {
        const int r = idx >> 7, c = idx & 127;
        const float cv = bt_pair[c] + b_dgram[c] + b_rel[c];
        const float wc = w_rel[(67 + r) * 128 + c];
        Etab[r][c] = cv + ((r < 5) ? (w_rel[66 * 128 + c] + wc) : wc);
    }

    // ---- per-pair packed indices: thread tid -> pair (i, j0+tid) ----
    {
        const int j  = j0 + tid;
        const int ai = (aatype[i] == 7) ? 1 : 3;   // GLY -> CA else CB
        const int aj = (aatype[j] == 7) ? 1 : 3;
        const float* pi = prev_pos + ((long)i * 37 + ai) * 3;
        const float* pj = prev_pos + ((long)j * 37 + aj) * 3;
        const float dx = pi[0] - pj[0];
        const float dy = pi[1] - pj[1];
        const float dz = pi[2] - pj[2];
        const float d2 = dx * dx + dy * dy + dz * dz;

        int bin = -1;
        #pragma unroll
        for (int b = 0; b < 15; ++b) {
            const float lo = 3.25f + 1.25f * (float)b;
            const float l2 = lo * lo;
            const float hi = lo + 1.25f;
            const float u2 = (b == 14) ? 1e8f : hi * hi;
            if (d2 > l2 && d2 < u2) bin = b;       // strict, matches reference
        }

        const bool asame = asym_id[i] == asym_id[j];
        int off = residue_index[i] - residue_index[j] + 32;
        off = min(max(off, 0), 64);
        const int p = asame ? off : 65;

        const bool esame = entity_id[i] == entity_id[j];
        int ch = sym_id[i] - sym_id[j] + 2;
        ch = min(max(ch, 0), 4);
        const int eidx = esame ? ch : 5;

        packs[tid] = (unsigned short)((bin + 1) | (p << 4) | (eidx << 11));
    }

    // ---- persistent per-lane channel vectors ----
    const int lane = tid & 63;
    const int wid  = tid >> 6;
    const int g    = lane >> 4;
    const int t    = lane & 15;
    const int c0   = t * 4;
    const int c1   = c0 + 64;

    const float4 gp0 = *(const float4*)(g_pair + c0);
    const float4 gp1 = *(const float4*)(g_pair + c1);

    __syncthreads();

    const float* rowp = prev_pair + ((long)i * NRES + j0) * CPAIR;
    float*       outp = out_pair + ((long)i * NRES + j0) * CPAIR;

    #pragma unroll 2
    for (int k = 0; k < 16; ++k) {
        const int pl = (wid << 6) | (k << 2) | g;      // pair within block
        const unsigned int pk = packs[pl];             // LDS broadcast in group
        const int bidx = pk & 15;
        const int p    = (pk >> 4) & 127;
        const int eidx = (pk >> 11) & 7;

        const float* xp = rowp + (long)pl * CPAIR;
        const float4 x0 = *(const float4*)(xp + c0);
        const float4 x1 = *(const float4*)(xp + c1);

        const float* wr = w_rel + p * 128;
        const float4 w0 = *(const float4*)(wr + c0);
        const float4 w1 = *(const float4*)(wr + c1);
        const float4 d0 = *(const float4*)(&Dtab[bidx][c0]);
        const float4 d1 = *(const float4*)(&Dtab[bidx][c1]);
        const float4 e0 = *(const float4*)(&Etab[eidx][c0]);
        const float4 e1 = *(const float4*)(&Etab[eidx][c1]);

        // one-pass stats: s = sum(x), q = sum(x^2); two independent DPP chains
        float s = ((x0.x + x0.y) + (x0.z + x0.w)) + ((x1.x + x1.y) + (x1.z + x1.w));
        float q = ((x0.x * x0.x + x0.y * x0.y) + (x0.z * x0.z + x0.w * x0.w)) +
                  ((x1.x * x1.x + x1.y * x1.y) + (x1.z * x1.z + x1.w * x1.w));
        s = dpp_rot_add<0x121>(s); q = dpp_rot_add<0x121>(q);  // ror 1
        s = dpp_rot_add<0x122>(s); q = dpp_rot_add<0x122>(q);  // ror 2
        s = dpp_rot_add<0x124>(s); q = dpp_rot_add<0x124>(q);  // ror 4
        s = dpp_rot_add<0x128>(s); q = dpp_rot_add<0x128>(q);  // ror 8

        const float mu = s * (1.0f / 128.0f);
        const float var = q * (1.0f / 128.0f) - mu * mu;
        const float rstd = rsqrtf(var + 1e-5f);

        const float v0 = x0.x - mu, v1 = x0.y - mu, v2 = x0.z - mu, v3 = x0.w - mu;
        const float v4 = x1.x - mu, v5 = x1.y - mu, v6 = x1.z - mu, v7 = x1.w - mu;

        float4 o0, o1;
        o0.x = v0 * rstd * gp0.x + (d0.x + w0.x + e0.x);
        o0.y = v1 * rstd * gp0.y + (d0.y + w0.y + e0.y);
        o0.z = v2 * rstd * gp0.z + (d0.z + w0.z + e0.z);
        o0.w = v3 * rstd * gp0.w + (d0.w + w0.w + e0.w);
        o1.x = v4 * rstd * gp1.x + (d1.x + w1.x + e1.x);
        o1.y = v5 * rstd * gp1.y + (d1.y + w1.y + e1.y);
        o1.z = v6 * rstd * gp1.z + (d1.z + w1.z + e1.z);
        o1.w = v7 * rstd * gp1.w + (d1.w + w1.w + e1.w);

        float* op = outp + (long)pl * CPAIR;
        *(float4*)(op + c0) = o0;
        *(float4*)(op + c1) = o1;
    }
}

// One wave64 per residue row; lane l holds channels 4l..4l+3 (float4).
__global__ __launch_bounds__(256) void msa_kernel(
    const float* __restrict__ prev_msa,
    const float* __restrict__ g_msa,
    const float* __restrict__ bt_msa,
    float* __restrict__ out_msa)
{
    const int lane = threadIdx.x & 63;
    const int row = (int)((blockIdx.x * blockDim.x + threadIdx.x) >> 6);
    if (row >= NRES) return;

    const int c = lane * 4;
    const long base = (long)row * CMSA + c;
    const float4 x = *(const float4*)(prev_msa + base);

    float s = (x.x + x.y) + (x.z + x.w);
    #pragma unroll
    for (int m = 32; m >= 1; m >>= 1) s += __shfl_xor(s, m);
    const float mu = s * (1.0f / 256.0f);

    const float a0 = x.x - mu, a1 = x.y - mu, a2 = x.z - mu, a3 = x.w - mu;
    float v = (a0 * a0 + a1 * a1) + (a2 * a2 + a3 * a3);
    #pragma unroll
    for (int m = 32; m >= 1; m >>= 1) v += __shfl_xor(v, m);
    const float rstd = rsqrtf(v * (1.0f / 256.0f) + 1e-5f);

    const float4 g  = *(const float4*)(g_msa  + c);
    const float4 bt = *(const float4*)(bt_msa + c);
    float4 o;
    o.x = a0 * rstd * g.x + bt.x;
    o.y = a1 * rstd * g.y + bt.y;
    o.z = a2 * rstd * g.z + bt.z;
    o.w = a3 * rstd * g.w + bt.w;
    *(float4*)(out_msa + base) = o;
}

extern "C" void kernel_launch(void* const* d_in, const int* in_sizes, int n_in,
                              void* d_out, int out_size, void* d_ws, size_t ws_size,
                              hipStream_t stream) {
    const int*   aatype        = (const int*)d_in[0];
    const int*   residue_index = (const int*)d_in[1];
    const int*   asym_id       = (const int*)d_in[2];
    const int*   entity_id     = (const int*)d_in[3];
    const int*   sym_id        = (const int*)d_in[4];
    const float* prev_pos      = (const float*)d_in[5];
    const float* prev_pair     = (const float*)d_in[6];
    const float* prev_msa      = (const float*)d_in[7];
    const float* w_dgram       = (const float*)d_in[8];
    const float* b_dgram       = (const float*)d_in[9];
    const float* g_pair        = (const float*)d_in[10];
    const float* bt_pair       = (const float*)d_in[11];
    const float* g_msa         = (const float*)d_in[12];
    const float* bt_msa        = (const float*)d_in[13];
    const float* w_rel         = (const float*)d_in[14];
    const float* b_rel         = (const float*)d_in[15];

    float* out_msa  = (float*)d_out;                       // [768,256] first
    float* out_pair = out_msa + (long)NRES * CMSA;         // then [768,768,128]

    msa_kernel<<<(NRES * 64 + 255) / 256, 256, 0, stream>>>(
        prev_msa, g_msa, bt_msa, out_msa);

    pair_kernel<<<NRES * 3, 256, 0, stream>>>(
        aatype, residue_index, asym_id, entity_id, sym_id,
        prev_pos, prev_pair,
        w_dgram, b_dgram, g_pair, bt_pair, w_rel, b_rel,
        out_pair);
}